// Round 8
// baseline (317.883 us; speedup 1.0000x reference)
//
#include <hip/hip_runtime.h>

#define NNODES 50000
#define NEDGES 800000
#define NGRAPHS 2048

typedef __attribute__((ext_vector_type(8))) short bf16x8;
typedef __attribute__((ext_vector_type(4))) float f32x4;

__device__ __forceinline__ float bf2f(ushort u) {
    return __uint_as_float(((uint)u) << 16);
}
__device__ __forceinline__ ushort f2bf(float f) {
    uint u = __float_as_uint(f);
    return (ushort)((u + 0x7fff + ((u >> 16) & 1)) >> 16);  // RNE
}

// ---------------- degree ----------------
__global__ void deg_count(const int* __restrict__ dst, int* __restrict__ cnt, int E) {
    int e = blockIdx.x * blockDim.x + threadIdx.x;
    if (e < E) atomicAdd(&cnt[dst[e]], 1);
}

// ---------------- CSR build ----------------
__global__ void block_scan(const int* __restrict__ cnt, int* __restrict__ lp,
                           int* __restrict__ bsum, int M) {
    __shared__ int s[256];
    int t = threadIdx.x;
    int n = blockIdx.x * 256 + t;
    int v = (n < M) ? cnt[n] : 0;
    s[t] = v;
    __syncthreads();
    #pragma unroll
    for (int off = 1; off < 256; off <<= 1) {
        int u = (t >= off) ? s[t - off] : 0;
        __syncthreads();
        s[t] += u;
        __syncthreads();
    }
    if (n < M) lp[n] = s[t] - v;
    if (t == 255) bsum[blockIdx.x] = s[255];
}

__global__ void scan_bsum(int* __restrict__ bsum, int NB) {
    __shared__ int s[256];
    int t = threadIdx.x;
    int v = (t < NB) ? bsum[t] : 0;
    s[t] = v;
    __syncthreads();
    #pragma unroll
    for (int off = 1; off < 256; off <<= 1) {
        int u = (t >= off) ? s[t - off] : 0;
        __syncthreads();
        s[t] += u;
        __syncthreads();
    }
    if (t < NB) bsum[t] = s[t] - v;
}

// rowptr finalize + cursor init + dis = rsqrt(deg+1) fused
__global__ void finalize_rowptr(int* __restrict__ rowptr, int* __restrict__ cursor,
                                const int* __restrict__ bsum, const int* __restrict__ cnt,
                                float* __restrict__ dis, int M, int E) {
    int n = blockIdx.x * blockDim.x + threadIdx.x;
    if (n < M) {
        int v = rowptr[n] + bsum[n >> 8];
        rowptr[n] = v;
        cursor[n] = v;
        dis[n] = rsqrtf((float)(cnt[n] + 1));
    }
    if (n == 0) rowptr[M] = E;
}

// packed (src, norm) single 8B store per edge
__global__ void fill_csr(const int* __restrict__ src, const int* __restrict__ dst,
                         const float* __restrict__ dis, int* __restrict__ cursor,
                         int2* __restrict__ csr, int E) {
    int e = blockIdx.x * blockDim.x + threadIdx.x;
    if (e >= E) return;
    int s = src[e], d = dst[e];
    int pos = atomicAdd(&cursor[d], 1);
    csr[pos] = make_int2(s, __float_as_int(dis[s] * dis[d]));
}

// ---------------- input cast / weight prep ----------------
__global__ void cast_x(const float* __restrict__ x, ushort* __restrict__ xb,
                       int M, int K, int Kp) {
    int idx = blockIdx.x * blockDim.x + threadIdx.x;
    if (idx >= M * Kp) return;
    int n = idx / Kp, k = idx % Kp;
    xb[idx] = (k < K) ? f2bf(x[(size_t)n * K + k]) : (ushort)0;
}

// Wt[n][k] = W[k][n], bf16, zero-padded to [Np][Kp]
__global__ void prep_w(const float* __restrict__ W, ushort* __restrict__ Wt,
                       int K, int N, int Kp, int Np) {
    int idx = blockIdx.x * blockDim.x + threadIdx.x;
    if (idx >= Kp * Np) return;
    int n = idx / Kp, k = idx % Kp;
    Wt[idx] = (k < K && n < N) ? f2bf(W[(size_t)k * N + n]) : (ushort)0;
}

__device__ __forceinline__ void acc8(float* acc, uint4 v, float nm) {
    acc[0] += bf2f((ushort)(v.x & 0xffff)) * nm;
    acc[1] += bf2f((ushort)(v.x >> 16)) * nm;
    acc[2] += bf2f((ushort)(v.y & 0xffff)) * nm;
    acc[3] += bf2f((ushort)(v.y >> 16)) * nm;
    acc[4] += bf2f((ushort)(v.z & 0xffff)) * nm;
    acc[5] += bf2f((ushort)(v.z >> 16)) * nm;
    acc[6] += bf2f((ushort)(v.w & 0xffff)) * nm;
    acc[7] += bf2f((ushort)(v.w >> 16)) * nm;
}

// ---------------- fused layer: gather 32-node A-tile into LDS, then MFMA GEMM ----
// hsrc: [M][CH] uint4 rows. LDS A: [32][KP+8] ushort, 16B-chunk XOR swizzle.
// hdst = relu(Ahat_tile @ Wt^T + bias) bf16 [M][NP], cols >= NREAL zeroed.
template <int CH, int SUB, int KP, int NP, int NREAL>
__global__ __launch_bounds__(256, 6) void fused_layer(const uint4* __restrict__ hsrc,
                                                      const int* __restrict__ rowptr,
                                                      const int2* __restrict__ csr,
                                                      const float* __restrict__ dis,
                                                      const ushort* __restrict__ Bt,
                                                      const float* __restrict__ bias,
                                                      ushort* __restrict__ hdst) {
    constexpr int WPAD = KP + 8;       // pad keeps frag reads at free 2-way conflicts
    constexpr int CHOUT = KP / 8;      // 16B chunks per LDS row
    constexpr int NT = (NP + 63) / 64; // N tiles
    __shared__ ushort Alds[32 * WPAD];
    __shared__ ushort Bsl[64 * 32];
    const int tid = threadIdx.x;
    const int lane = tid & 63;
    const int wid = tid >> 6;
    const int base = blockIdx.x * 32;

    // ---------- gather phase: wave wid gathers rows wid*8 .. wid*8+7 ----------
    {
        int sub = lane / CH;
        int ch = lane % CH;
        bool active = sub < SUB;
        #pragma unroll 1
        for (int s = 0; s < 8; ++s) {
            int r = wid * 8 + s;
            int node = base + r;
            int beg = 0, end = 0;
            if (node < NNODES) { beg = rowptr[node]; end = rowptr[node + 1]; }
            float acc[8] = {};
            for (int i = beg; i < end; i += 4 * SUB) {
                int2 ev[4];
                int vld[4];
                #pragma unroll
                for (int u = 0; u < 4; ++u) {
                    int e = i + u * SUB + sub;
                    vld[u] = active && (e < end);
                    ev[u] = vld[u] ? csr[e] : make_int2(0, 0);
                }
                uint4 av[4];
                #pragma unroll
                for (int u = 0; u < 4; ++u)
                    av[u] = vld[u] ? hsrc[(size_t)ev[u].x * CH + ch] : make_uint4(0, 0, 0, 0);
                #pragma unroll
                for (int u = 0; u < 4; ++u)
                    acc8(acc, av[u], __int_as_float(ev[u].y));
            }
            // reduce partials across sub groups
            float tot[8];
            #pragma unroll
            for (int j = 0; j < 8; ++j) tot[j] = acc[j];
            #pragma unroll
            for (int sb = 1; sb < SUB; ++sb) {
                int srcLane = ch + sb * CH;
                #pragma unroll
                for (int j = 0; j < 8; ++j) tot[j] += __shfl(acc[j], srcLane);
            }
            if (lane < CHOUT) {
                uint4 o = make_uint4(0, 0, 0, 0);
                if (lane < CH && node < NNODES) {
                    float di = dis[node];
                    float d2 = di * di;
                    uint4 hs = hsrc[(size_t)node * CH + lane];
                    tot[0] += bf2f((ushort)(hs.x & 0xffff)) * d2;
                    tot[1] += bf2f((ushort)(hs.x >> 16)) * d2;
                    tot[2] += bf2f((ushort)(hs.y & 0xffff)) * d2;
                    tot[3] += bf2f((ushort)(hs.y >> 16)) * d2;
                    tot[4] += bf2f((ushort)(hs.z & 0xffff)) * d2;
                    tot[5] += bf2f((ushort)(hs.z >> 16)) * d2;
                    tot[6] += bf2f((ushort)(hs.w & 0xffff)) * d2;
                    tot[7] += bf2f((ushort)(hs.w >> 16)) * d2;
                    o.x = (uint)f2bf(tot[0]) | ((uint)f2bf(tot[1]) << 16);
                    o.y = (uint)f2bf(tot[2]) | ((uint)f2bf(tot[3]) << 16);
                    o.z = (uint)f2bf(tot[4]) | ((uint)f2bf(tot[5]) << 16);
                    o.w = (uint)f2bf(tot[6]) | ((uint)f2bf(tot[7]) << 16);
                }
                int g = lane >> 2, c = lane & 3;
                int sw = c ^ ((r >> 1) & 3);
                *(uint4*)&Alds[r * WPAD + g * 32 + sw * 8] = o;
            }
        }
    }
    __syncthreads();

    // ---------- GEMM phase: C[32 x NP] = Alds @ Bt^T ----------
    const int wm = (wid >> 1) * 16;
    const int wn = (wid & 1) * 32;
    const int sr = tid >> 2;
    const int sc = tid & 3;
    const int swz = sc ^ ((sr >> 1) & 3);
    for (int bn = 0; bn < NT; ++bn) {
        f32x4 acc2[2] = {};
        for (int k0 = 0; k0 < KP; k0 += 32) {
            bf16x8 bv = {};
            int gn = bn * 64 + sr;
            if (gn < NP) bv = *(const bf16x8*)&Bt[(size_t)gn * KP + k0 + sc * 8];
            *(bf16x8*)&Bsl[sr * 32 + swz * 8] = bv;
            __syncthreads();
            int lc = lane >> 4;
            int ar = wm + (lane & 15);
            int apc = lc ^ ((ar >> 1) & 3);
            bf16x8 af = *(const bf16x8*)&Alds[ar * WPAD + k0 + apc * 8];
            bf16x8 bfr[2];
            #pragma unroll
            for (int n = 0; n < 2; ++n) {
                int rr = wn + n * 16 + (lane & 15);
                int pc = lc ^ ((rr >> 1) & 3);
                bfr[n] = *(const bf16x8*)&Bsl[rr * 32 + pc * 8];
            }
            acc2[0] = __builtin_amdgcn_mfma_f32_16x16x32_bf16(af, bfr[0], acc2[0], 0, 0, 0);
            acc2[1] = __builtin_amdgcn_mfma_f32_16x16x32_bf16(af, bfr[1], acc2[1], 0, 0, 0);
            __syncthreads();
        }
        #pragma unroll
        for (int n = 0; n < 2; ++n) {
            int gc = bn * 64 + wn + n * 16 + (lane & 15);
            #pragma unroll
            for (int j = 0; j < 4; ++j) {
                int gr = base + wm + (lane >> 4) * 4 + j;
                if (gr < NNODES && gc < NP) {
                    float v = acc2[n][j];
                    float o = (gc < NREAL) ? fmaxf(v + bias[gc], 0.f) : 0.f;
                    hdst[(size_t)gr * NP + gc] = f2bf(o);
                }
            }
        }
    }
}

// ---------------- MFMA bf16 GEMM (FC): C = relu(A@Wt^T + bias) + addend, f32 out ----
__global__ __launch_bounds__(256) void gemm_fc(const ushort* __restrict__ A,
                                               const ushort* __restrict__ Bt,
                                               float* __restrict__ Cf,
                                               const float* __restrict__ bias,
                                               const float* __restrict__ addend,
                                               int M, int Kp, int Np, int Nreal) {
    __shared__ ushort Asl[64 * 32];
    __shared__ ushort Bsl[64 * 32];
    const int tid = threadIdx.x;
    const int lane = tid & 63;
    const int wid = tid >> 6;
    const int wm = (wid >> 1) * 32, wn = (wid & 1) * 32;
    const int bm = blockIdx.x * 64, bn = blockIdx.y * 64;

    const int sr = tid >> 2;
    const int sc = tid & 3;
    const int swz = sc ^ ((sr >> 1) & 3);
    const int lc = lane >> 4;

    f32x4 acc[2][2] = {};
    for (int k0 = 0; k0 < Kp; k0 += 32) {
        bf16x8 av = {};
        int gr = bm + sr;
        if (gr < M) av = *(const bf16x8*)&A[(size_t)gr * Kp + k0 + sc * 8];
        *(bf16x8*)&Asl[sr * 32 + swz * 8] = av;
        bf16x8 bv = {};
        int gn = bn + sr;
        if (gn < Np) bv = *(const bf16x8*)&Bt[(size_t)gn * Kp + k0 + sc * 8];
        *(bf16x8*)&Bsl[sr * 32 + swz * 8] = bv;
        __syncthreads();
        bf16x8 af[2], bfr[2];
        #pragma unroll
        for (int m = 0; m < 2; ++m) {
            int r = wm + m * 16 + (lane & 15);
            int pc = lc ^ ((r >> 1) & 3);
            af[m] = *(const bf16x8*)&Asl[r * 32 + pc * 8];
        }
        #pragma unroll
        for (int n = 0; n < 2; ++n) {
            int r = wn + n * 16 + (lane & 15);
            int pc = lc ^ ((r >> 1) & 3);
            bfr[n] = *(const bf16x8*)&Bsl[r * 32 + pc * 8];
        }
        #pragma unroll
        for (int m = 0; m < 2; ++m)
            #pragma unroll
            for (int n = 0; n < 2; ++n)
                acc[m][n] = __builtin_amdgcn_mfma_f32_16x16x32_bf16(af[m], bfr[n], acc[m][n], 0, 0, 0);
        __syncthreads();
    }
    #pragma unroll
    for (int m = 0; m < 2; ++m) {
        #pragma unroll
        for (int n = 0; n < 2; ++n) {
            int gc = bn + wn + n * 16 + (lane & 15);
            #pragma unroll
            for (int j = 0; j < 4; ++j) {
                int gr = bm + wm + m * 16 + (lane >> 4) * 4 + j;
                if (gr >= M || gc >= Nreal) continue;
                float v = acc[m][n][j];
                float o = fmaxf(v + bias[gc], 0.f) + addend[(size_t)gr * Nreal + gc];
                Cf[(size_t)gr * Nreal + gc] = o;
            }
        }
    }
}

// ---------------- per-graph segment bounds (batch is sorted) ----------------
__global__ void graph_bounds(const int* __restrict__ batch, int* __restrict__ gstart,
                             int M, int G) {
    int n = blockIdx.x * blockDim.x + threadIdx.x;
    if (n >= M) return;
    int b = batch[n];
    int bp = (n == 0) ? -1 : batch[n - 1];
    for (int gg = bp + 1; gg <= b; ++gg) gstart[gg] = n;
    if (n == M - 1) {
        for (int gg = b + 1; gg <= G; ++gg) gstart[gg] = M;
    }
}

// ---------------- segmented max pool: block per graph, bf16 out ----------------
__global__ void pool_max_seg(const uint* __restrict__ h3, const int* __restrict__ gstart,
                             uint* __restrict__ gb, int PAIRS) {
    int g = blockIdx.x;
    int s = gstart[g], e = gstart[g + 1];
    for (int p = threadIdx.x; p < PAIRS; p += blockDim.x) {
        float mL = 0.f, mH = 0.f;  // h3 >= 0; empty graph -> 0 (isfinite guard)
        for (int n = s; n < e; ++n) {
            uint v = h3[(size_t)n * PAIRS + p];
            mL = fmaxf(mL, bf2f((ushort)(v & 0xffff)));
            mH = fmaxf(mH, bf2f((ushort)(v >> 16)));
        }
        gb[(size_t)g * PAIRS + p] = (uint)f2bf(mL) | ((uint)f2bf(mH) << 16);
    }
}

extern "C" void kernel_launch(void* const* d_in, const int* in_sizes, int n_in,
                              void* d_out, int out_size, void* d_ws, size_t ws_size,
                              hipStream_t stream) {
    const float* x     = (const float*)d_in[0];
    const int*   eidx  = (const int*)d_in[1];
    const int*   batch = (const int*)d_in[2];
    const float* drug2 = (const float*)d_in[3];
    const float* W1 = (const float*)d_in[4];
    const float* b1 = (const float*)d_in[5];
    const float* W2 = (const float*)d_in[6];
    const float* b2 = (const float*)d_in[7];
    const float* W3 = (const float*)d_in[8];
    const float* b3 = (const float*)d_in[9];
    const float* Wfc = (const float*)d_in[10];
    const float* bfc = (const float*)d_in[11];
    float* out = (float*)d_out;

    const int M = NNODES, E = NEDGES, G = NGRAPHS;
    const int F1 = 78, F2 = 156, F3 = 312, FC = 489;
    const int Kx = 80;                 // xb / h1 storage width
    const int Kp1 = 96, Np1 = 80;
    const int Kp2 = 96, Np2 = 160;
    const int Kp3 = 160, Np3 = 320;
    const int Kpf = 320, Npf = 496;

    const int* src = eidx;
    const int* dst = eidx + E;
    const int NB = (M + 255) / 256;

    char* ws = (char*)d_ws;
    size_t off = 0;
    auto alloc = [&](size_t bytes) {
        void* p = ws + off;
        off += (bytes + 255) & ~(size_t)255;
        return p;
    };
    ushort* xb   = (ushort*)alloc((size_t)M * Kx * 2);
    ushort* h1   = (ushort*)alloc((size_t)M * Np1 * 2);
    ushort* h2   = (ushort*)alloc((size_t)M * Np2 * 2);
    ushort* h3   = (ushort*)alloc((size_t)M * Np3 * 2);
    ushort* W1t  = (ushort*)alloc((size_t)Np1 * Kp1 * 2);
    ushort* W2t  = (ushort*)alloc((size_t)Np2 * Kp2 * 2);
    ushort* W3t  = (ushort*)alloc((size_t)Np3 * Kp3 * 2);
    ushort* Wfct = (ushort*)alloc((size_t)Npf * Kpf * 2);
    ushort* gb   = (ushort*)alloc((size_t)G * Kpf * 2);
    float* dis    = (float*)alloc((size_t)M * 4);
    int*   cnt    = (int*)alloc((size_t)M * 4);
    int*   rowptr = (int*)alloc((size_t)(M + 1) * 4);
    int*   cursor = (int*)alloc((size_t)M * 4);
    int*   bsum   = (int*)alloc(1024);
    int2*  csr    = (int2*)alloc((size_t)E * 8);
    int*   gstart  = (int*)alloc((size_t)(G + 1) * 4);

    // ---- CSR build + per-graph bounds
    hipMemsetAsync(cnt, 0, (size_t)M * 4, stream);
    deg_count<<<(E + 255) / 256, 256, 0, stream>>>(dst, cnt, E);
    block_scan<<<NB, 256, 0, stream>>>(cnt, rowptr, bsum, M);
    scan_bsum<<<1, 256, 0, stream>>>(bsum, NB);
    finalize_rowptr<<<NB, 256, 0, stream>>>(rowptr, cursor, bsum, cnt, dis, M, E);
    fill_csr<<<(E + 255) / 256, 256, 0, stream>>>(src, dst, dis, cursor, csr, E);
    graph_bounds<<<NB, 256, 0, stream>>>(batch, gstart, M, G);

    // ---- casts / weight prep
    cast_x<<<(M * Kx + 255) / 256, 256, 0, stream>>>(x, xb, M, F1, Kx);
    prep_w<<<(Np1 * Kp1 + 255) / 256, 256, 0, stream>>>(W1, W1t, F1, F1, Kp1, Np1);
    prep_w<<<(Np2 * Kp2 + 255) / 256, 256, 0, stream>>>(W2, W2t, F1, F2, Kp2, Np2);
    prep_w<<<(Np3 * Kp3 + 255) / 256, 256, 0, stream>>>(W3, W3t, F2, F3, Kp3, Np3);
    prep_w<<<(Npf * Kpf + 255) / 256, 256, 0, stream>>>(Wfc, Wfct, F3, FC, Kpf, Npf);

    const int GF = (M + 31) / 32;   // fused-layer grid: 32 nodes per block

    // ---- layer 1: h1 = relu(Ahat@xb @ W1 + b1), bf16 [M][80]
    fused_layer<10, 6, 96, 80, 78><<<GF, 256, 0, stream>>>(
        (const uint4*)xb, rowptr, csr, dis, W1t, b1, h1);

    // ---- layer 2: h2 = relu(Ahat@h1 @ W2 + b2), bf16 [M][160]
    fused_layer<10, 6, 96, 160, 156><<<GF, 256, 0, stream>>>(
        (const uint4*)h1, rowptr, csr, dis, W2t, b2, h2);

    // ---- layer 3: h3 = relu(Ahat@h2 @ W3 + b3), bf16 [M][320]
    fused_layer<20, 3, 160, 320, 312><<<GF, 256, 0, stream>>>(
        (const uint4*)h2, rowptr, csr, dis, W3t, b3, h3);

    // ---- segmented max pool -> gb bf16 [G][320]
    pool_max_seg<<<G, 256, 0, stream>>>((const uint*)h3, gstart, (uint*)gb, Kpf / 2);

    // ---- FC: out = relu(gb@Wfc+bfc)+drug2, f32 [2048][489]
    gemm_fc<<<dim3((G + 63) / 64, (Npf + 63) / 64), 256, 0, stream>>>(
        gb, Wfct, out, bfc, drug2, G, Kpf, Npf, FC);
}

// Round 9
// 285.328 us; speedup vs baseline: 1.1141x; 1.1141x over previous
//
#include <hip/hip_runtime.h>

#define NNODES 50000
#define NEDGES 800000
#define NGRAPHS 2048

typedef __attribute__((ext_vector_type(8))) short bf16x8;
typedef __attribute__((ext_vector_type(4))) float f32x4;

__device__ __forceinline__ float bf2f(ushort u) {
    return __uint_as_float(((uint)u) << 16);
}
__device__ __forceinline__ ushort f2bf(float f) {
    uint u = __float_as_uint(f);
    return (ushort)((u + 0x7fff + ((u >> 16) & 1)) >> 16);  // RNE
}

// ---------------- degree ----------------
__global__ void deg_count(const int* __restrict__ dst, int* __restrict__ cnt, int E) {
    int e = blockIdx.x * blockDim.x + threadIdx.x;
    if (e < E) atomicAdd(&cnt[dst[e]], 1);
}

// ---------------- CSR build ----------------
__global__ void block_scan(const int* __restrict__ cnt, int* __restrict__ lp,
                           int* __restrict__ bsum, int M) {
    __shared__ int s[256];
    int t = threadIdx.x;
    int n = blockIdx.x * 256 + t;
    int v = (n < M) ? cnt[n] : 0;
    s[t] = v;
    __syncthreads();
    #pragma unroll
    for (int off = 1; off < 256; off <<= 1) {
        int u = (t >= off) ? s[t - off] : 0;
        __syncthreads();
        s[t] += u;
        __syncthreads();
    }
    if (n < M) lp[n] = s[t] - v;
    if (t == 255) bsum[blockIdx.x] = s[255];
}

__global__ void scan_bsum(int* __restrict__ bsum, int NB) {
    __shared__ int s[256];
    int t = threadIdx.x;
    int v = (t < NB) ? bsum[t] : 0;
    s[t] = v;
    __syncthreads();
    #pragma unroll
    for (int off = 1; off < 256; off <<= 1) {
        int u = (t >= off) ? s[t - off] : 0;
        __syncthreads();
        s[t] += u;
        __syncthreads();
    }
    if (t < NB) bsum[t] = s[t] - v;
}

// rowptr finalize + cursor init + dis + per-graph bounds, one pass over M
__global__ void finalize_rowptr(int* __restrict__ rowptr, int* __restrict__ cursor,
                                const int* __restrict__ bsum, const int* __restrict__ cnt,
                                float* __restrict__ dis,
                                const int* __restrict__ batch, int* __restrict__ gstart,
                                int M, int E, int G) {
    int n = blockIdx.x * blockDim.x + threadIdx.x;
    if (n < M) {
        int v = rowptr[n] + bsum[n >> 8];
        rowptr[n] = v;
        cursor[n] = v;
        dis[n] = rsqrtf((float)(cnt[n] + 1));
        int b = batch[n];
        int bp = (n == 0) ? -1 : batch[n - 1];
        for (int gg = bp + 1; gg <= b; ++gg) gstart[gg] = n;
        if (n == M - 1) {
            for (int gg = b + 1; gg <= G; ++gg) gstart[gg] = M;
        }
    }
    if (n == 0) rowptr[M] = E;
}

// packed (src, norm) single 8B store per edge
__global__ void fill_csr(const int* __restrict__ src, const int* __restrict__ dst,
                         const float* __restrict__ dis, int* __restrict__ cursor,
                         int2* __restrict__ csr, int E) {
    int e = blockIdx.x * blockDim.x + threadIdx.x;
    if (e >= E) return;
    int s = src[e], d = dst[e];
    int pos = atomicAdd(&cursor[d], 1);
    csr[pos] = make_int2(s, __float_as_int(dis[s] * dis[d]));
}

// ---------------- combined input cast + weight prep (one launch) ----------------
// work layout (flat thread index):
//   [0, M*KX)                : xb
//   then W1t, W2t, W3t, Wfct  (each [Np][Kp] from [K][N])
__global__ void prep_all(const float* __restrict__ x, ushort* __restrict__ xb,
                         const float* __restrict__ W1, ushort* __restrict__ W1t,
                         const float* __restrict__ W2, ushort* __restrict__ W2t,
                         const float* __restrict__ W3, ushort* __restrict__ W3t,
                         const float* __restrict__ Wfc, ushort* __restrict__ Wfct) {
    const int M = NNODES;
    const int KX = 80, F1 = 78, F2 = 156, F3 = 312, FC = 489;
    const int n0 = M * KX;                       // xb
    const int n1 = 80 * 96, n2 = 160 * 96, n3 = 320 * 160, n4 = 496 * 320;
    int idx = blockIdx.x * blockDim.x + threadIdx.x;
    if (idx < n0) {
        int n = idx / KX, k = idx % KX;
        xb[idx] = (k < F1) ? f2bf(x[(size_t)n * F1 + k]) : (ushort)0;
        return;
    }
    idx -= n0;
    if (idx < n1) {
        int n = idx / 96, k = idx % 96;
        W1t[idx] = (k < F1 && n < F1) ? f2bf(W1[(size_t)k * F1 + n]) : (ushort)0;
        return;
    }
    idx -= n1;
    if (idx < n2) {
        int n = idx / 96, k = idx % 96;
        W2t[idx] = (k < F1 && n < F2) ? f2bf(W2[(size_t)k * F2 + n]) : (ushort)0;
        return;
    }
    idx -= n2;
    if (idx < n3) {
        int n = idx / 160, k = idx % 160;
        W3t[idx] = (k < F2 && n < F3) ? f2bf(W3[(size_t)k * F3 + n]) : (ushort)0;
        return;
    }
    idx -= n3;
    if (idx < n4) {
        int n = idx / 320, k = idx % 320;
        Wfct[idx] = (k < F3 && n < FC) ? f2bf(Wfc[(size_t)k * FC + n]) : (ushort)0;
    }
}

// ---------------- ILP gather (R5/R7-proven): lanes = (sub-edge, uint4-chunk) ----
// 2 nodes per 128-thread block. STR = source row stride in uint4 (>= CH).
__device__ __forceinline__ void acc8(float* acc, uint4 v, float nm) {
    acc[0] += bf2f((ushort)(v.x & 0xffff)) * nm;
    acc[1] += bf2f((ushort)(v.x >> 16)) * nm;
    acc[2] += bf2f((ushort)(v.y & 0xffff)) * nm;
    acc[3] += bf2f((ushort)(v.y >> 16)) * nm;
    acc[4] += bf2f((ushort)(v.z & 0xffff)) * nm;
    acc[5] += bf2f((ushort)(v.z >> 16)) * nm;
    acc[6] += bf2f((ushort)(v.w & 0xffff)) * nm;
    acc[7] += bf2f((ushort)(v.w >> 16)) * nm;
}

template <int CH, int STR, int SUB, int CHOUT>
__global__ __launch_bounds__(128) void gather_ilp(const uint4* __restrict__ h,
                                                  const int* __restrict__ rowptr,
                                                  const int2* __restrict__ csr,
                                                  const float* __restrict__ dis,
                                                  uint4* __restrict__ agg) {
    int node = blockIdx.x * 2 + (threadIdx.x >> 6);
    if (node >= NNODES) return;
    int lane = threadIdx.x & 63;
    int sub = lane / CH;
    int ch = lane % CH;
    bool active = sub < SUB;

    float acc[8] = {};
    int beg = rowptr[node], end = rowptr[node + 1];
    for (int i = beg; i < end; i += 4 * SUB) {
        int2 ev[4];
        int vld[4];
        #pragma unroll
        for (int u = 0; u < 4; ++u) {
            int e = i + u * SUB + sub;
            vld[u] = active && (e < end);
            ev[u] = vld[u] ? csr[e] : make_int2(0, 0);
        }
        uint4 av[4];
        #pragma unroll
        for (int u = 0; u < 4; ++u)
            av[u] = vld[u] ? h[(size_t)ev[u].x * STR + ch] : make_uint4(0, 0, 0, 0);
        #pragma unroll
        for (int u = 0; u < 4; ++u)
            acc8(acc, av[u], __int_as_float(ev[u].y));
    }

    float tot[8];
    #pragma unroll
    for (int j = 0; j < 8; ++j) tot[j] = acc[j];
    #pragma unroll
    for (int sb = 1; sb < SUB; ++sb) {
        int srcLane = ch + sb * CH;
        #pragma unroll
        for (int j = 0; j < 8; ++j) tot[j] += __shfl(acc[j], srcLane);
    }

    if (lane < CHOUT) {
        uint4 o = make_uint4(0, 0, 0, 0);
        if (lane < CH) {
            float di = dis[node];
            float d2 = di * di;
            uint4 hs = h[(size_t)node * STR + lane];
            tot[0] += bf2f((ushort)(hs.x & 0xffff)) * d2;
            tot[1] += bf2f((ushort)(hs.x >> 16)) * d2;
            tot[2] += bf2f((ushort)(hs.y & 0xffff)) * d2;
            tot[3] += bf2f((ushort)(hs.y >> 16)) * d2;
            tot[4] += bf2f((ushort)(hs.z & 0xffff)) * d2;
            tot[5] += bf2f((ushort)(hs.z >> 16)) * d2;
            tot[6] += bf2f((ushort)(hs.w & 0xffff)) * d2;
            tot[7] += bf2f((ushort)(hs.w >> 16)) * d2;
            o.x = (uint)f2bf(tot[0]) | ((uint)f2bf(tot[1]) << 16);
            o.y = (uint)f2bf(tot[2]) | ((uint)f2bf(tot[3]) << 16);
            o.z = (uint)f2bf(tot[4]) | ((uint)f2bf(tot[5]) << 16);
            o.w = (uint)f2bf(tot[6]) | ((uint)f2bf(tot[7]) << 16);
        }
        agg[(size_t)node * CHOUT + lane] = o;
    }
}

// ---------------- MFMA bf16 GEMM: C = epi(A[M][Kp] @ Wt[Np][Kp]^T) ----------------
// EPI=0: bf16 out, row stride Cld, relu(acc+bias) for col<Nreal else 0.
// EPI=1: f32 out [M][Nreal], relu(acc+bias)+addend.
template <int EPI>
__global__ __launch_bounds__(256) void gemm_mfma(const ushort* __restrict__ A,
                                                 const ushort* __restrict__ Bt,
                                                 ushort* __restrict__ Cb,
                                                 float* __restrict__ Cf,
                                                 const float* __restrict__ bias,
                                                 const float* __restrict__ addend,
                                                 int M, int Kp, int Np, int Nreal, int Cld) {
    __shared__ ushort Asl[64 * 32];
    __shared__ ushort Bsl[64 * 32];
    const int tid = threadIdx.x;
    const int lane = tid & 63;
    const int wid = tid >> 6;
    const int wm = (wid >> 1) * 32, wn = (wid & 1) * 32;
    const int bm = blockIdx.x * 64, bn = blockIdx.y * 64;

    const int sr = tid >> 2;
    const int sc = tid & 3;
    const int swz = sc ^ ((sr >> 1) & 3);
    const int lc = lane >> 4;

    f32x4 acc[2][2] = {};
    for (int k0 = 0; k0 < Kp; k0 += 32) {
        bf16x8 av = {};
        int gr = bm + sr;
        if (gr < M) av = *(const bf16x8*)&A[(size_t)gr * Kp + k0 + sc * 8];
        *(bf16x8*)&Asl[sr * 32 + swz * 8] = av;
        bf16x8 bv = {};
        int gn = bn + sr;
        if (gn < Np) bv = *(const bf16x8*)&Bt[(size_t)gn * Kp + k0 + sc * 8];
        *(bf16x8*)&Bsl[sr * 32 + swz * 8] = bv;
        __syncthreads();
        bf16x8 af[2], bfr[2];
        #pragma unroll
        for (int m = 0; m < 2; ++m) {
            int r = wm + m * 16 + (lane & 15);
            int pc = lc ^ ((r >> 1) & 3);
            af[m] = *(const bf16x8*)&Asl[r * 32 + pc * 8];
        }
        #pragma unroll
        for (int n = 0; n < 2; ++n) {
            int r = wn + n * 16 + (lane & 15);
            int pc = lc ^ ((r >> 1) & 3);
            bfr[n] = *(const bf16x8*)&Bsl[r * 32 + pc * 8];
        }
        #pragma unroll
        for (int m = 0; m < 2; ++m)
            #pragma unroll
            for (int n = 0; n < 2; ++n)
                acc[m][n] = __builtin_amdgcn_mfma_f32_16x16x32_bf16(af[m], bfr[n], acc[m][n], 0, 0, 0);
        __syncthreads();
    }
    #pragma unroll
    for (int m = 0; m < 2; ++m) {
        #pragma unroll
        for (int n = 0; n < 2; ++n) {
            int gc = bn + wn + n * 16 + (lane & 15);
            #pragma unroll
            for (int j = 0; j < 4; ++j) {
                int gr = bm + wm + m * 16 + (lane >> 4) * 4 + j;
                if (gr >= M) continue;
                float v = acc[m][n][j];
                if (EPI == 0) {
                    if (gc < Np) {
                        float o = (gc < Nreal) ? fmaxf(v + bias[gc], 0.f) : 0.f;
                        Cb[(size_t)gr * Cld + gc] = f2bf(o);
                    }
                } else {
                    if (gc < Nreal) {
                        float o = fmaxf(v + bias[gc], 0.f) + addend[(size_t)gr * Nreal + gc];
                        Cf[(size_t)gr * Nreal + gc] = o;
                    }
                }
            }
        }
    }
}

// ---------------- segmented max pool: block per graph, bf16 out ----------------
__global__ void pool_max_seg(const uint* __restrict__ h3, const int* __restrict__ gstart,
                             uint* __restrict__ gb, int PAIRS) {
    int g = blockIdx.x;
    int s = gstart[g], e = gstart[g + 1];
    for (int p = threadIdx.x; p < PAIRS; p += blockDim.x) {
        float mL = 0.f, mH = 0.f;  // h3 >= 0; empty graph -> 0 (isfinite guard)
        for (int n = s; n < e; ++n) {
            uint v = h3[(size_t)n * PAIRS + p];
            mL = fmaxf(mL, bf2f((ushort)(v & 0xffff)));
            mH = fmaxf(mH, bf2f((ushort)(v >> 16)));
        }
        gb[(size_t)g * PAIRS + p] = (uint)f2bf(mL) | ((uint)f2bf(mH) << 16);
    }
}

extern "C" void kernel_launch(void* const* d_in, const int* in_sizes, int n_in,
                              void* d_out, int out_size, void* d_ws, size_t ws_size,
                              hipStream_t stream) {
    const float* x     = (const float*)d_in[0];
    const int*   eidx  = (const int*)d_in[1];
    const int*   batch = (const int*)d_in[2];
    const float* drug2 = (const float*)d_in[3];
    const float* W1 = (const float*)d_in[4];
    const float* b1 = (const float*)d_in[5];
    const float* W2 = (const float*)d_in[6];
    const float* b2 = (const float*)d_in[7];
    const float* W3 = (const float*)d_in[8];
    const float* b3 = (const float*)d_in[9];
    const float* Wfc = (const float*)d_in[10];
    const float* bfc = (const float*)d_in[11];
    float* out = (float*)d_out;

    const int M = NNODES, E = NEDGES, G = NGRAPHS;
    const int F1 = 78, F2 = 156, F3 = 312, FC = 489;
    const int Kx = 80;                 // xb / h1 storage width (ushorts)
    const int Kp1 = 96, Np1 = 80;
    const int Kp2 = 96, Np2 = 160;
    const int Kp3 = 160, Np3 = 320;
    const int Kpf = 320, Npf = 496;
    const int S2 = 192;                // h2 row stride (384 B = 3 full lines)

    const int* src = eidx;
    const int* dst = eidx + E;
    const int NB = (M + 255) / 256;

    char* ws = (char*)d_ws;
    size_t off = 0;
    auto alloc = [&](size_t bytes) {
        void* p = ws + off;
        off += (bytes + 255) & ~(size_t)255;
        return p;
    };
    ushort* xb   = (ushort*)alloc((size_t)M * Kx * 2);
    ushort* h1   = (ushort*)alloc((size_t)M * Np1 * 2);
    ushort* h2   = (ushort*)alloc((size_t)M * S2 * 2);
    ushort* h3   = (ushort*)alloc((size_t)M * Np3 * 2);
    ushort* agg  = (ushort*)alloc((size_t)M * Kp3 * 2);
    ushort* W1t  = (ushort*)alloc((size_t)Np1 * Kp1 * 2);
    ushort* W2t  = (ushort*)alloc((size_t)Np2 * Kp2 * 2);
    ushort* W3t  = (ushort*)alloc((size_t)Np3 * Kp3 * 2);
    ushort* Wfct = (ushort*)alloc((size_t)Npf * Kpf * 2);
    ushort* gb   = (ushort*)alloc((size_t)G * Kpf * 2);
    float* dis    = (float*)alloc((size_t)M * 4);
    int*   cnt    = (int*)alloc((size_t)M * 4);
    int*   rowptr = (int*)alloc((size_t)(M + 1) * 4);
    int*   cursor = (int*)alloc((size_t)M * 4);
    int*   bsum   = (int*)alloc(1024);
    int2*  csr    = (int2*)alloc((size_t)E * 8);
    int*   gstart  = (int*)alloc((size_t)(G + 1) * 4);

    // ---- CSR build + bounds + dis (5 launches)
    hipMemsetAsync(cnt, 0, (size_t)M * 4, stream);
    deg_count<<<(E + 255) / 256, 256, 0, stream>>>(dst, cnt, E);
    block_scan<<<NB, 256, 0, stream>>>(cnt, rowptr, bsum, M);
    scan_bsum<<<1, 256, 0, stream>>>(bsum, NB);
    finalize_rowptr<<<NB, 256, 0, stream>>>(rowptr, cursor, bsum, cnt, dis, batch, gstart, M, E, G);
    fill_csr<<<(E + 255) / 256, 256, 0, stream>>>(src, dst, dis, cursor, csr, E);

    // ---- combined cast + weight prep (1 launch)
    {
        int total = M * Kx + 80 * 96 + 160 * 96 + 320 * 160 + 496 * 320;
        prep_all<<<(total + 255) / 256, 256, 0, stream>>>(x, xb, W1, W1t, W2, W2t, W3, W3t, Wfc, Wfct);
    }

    const int GG = (M + 1) / 2;       // 2 nodes per 128-thread block
    const int GMX = (M + 63) / 64;

    // ---- layer 1: agg [M][96]; h1 = relu(agg@W1+b1) [M][80]
    gather_ilp<10, 10, 6, 12><<<GG, 128, 0, stream>>>((const uint4*)xb, rowptr, csr, dis, (uint4*)agg);
    gemm_mfma<0><<<dim3(GMX, (Np1 + 63) / 64), 256, 0, stream>>>(agg, W1t, h1, nullptr, b1, nullptr, M, Kp1, Np1, F1, Np1);

    // ---- layer 2: agg [M][96]; h2 = relu(agg@W2+b2) [M][160] @ stride 192
    gather_ilp<10, 10, 6, 12><<<GG, 128, 0, stream>>>((const uint4*)h1, rowptr, csr, dis, (uint4*)agg);
    gemm_mfma<0><<<dim3(GMX, (Np2 + 63) / 64), 256, 0, stream>>>(agg, W2t, h2, nullptr, b2, nullptr, M, Kp2, Np2, F2, S2);

    // ---- layer 3: agg [M][160]; h3 = relu(agg@W3+b3) [M][320]
    gather_ilp<20, 24, 3, 20><<<GG, 128, 0, stream>>>((const uint4*)h2, rowptr, csr, dis, (uint4*)agg);
    gemm_mfma<0><<<dim3(GMX, Np3 / 64), 256, 0, stream>>>(agg, W3t, h3, nullptr, b3, nullptr, M, Kp3, Np3, F3, Np3);

    // ---- segmented max pool -> gb bf16 [G][320]
    pool_max_seg<<<G, 256, 0, stream>>>((const uint*)h3, gstart, (uint*)gb, Kpf / 2);

    // ---- FC: out = relu(gb@Wfc+bfc)+drug2, f32 [2048][489]
    gemm_mfma<1><<<dim3((G + 63) / 64, (Npf + 63) / 64), 256, 0, stream>>>(gb, Wfct, nullptr, out, bfc, drug2, G, Kpf, Npf, FC, 0);
}

// Round 10
// 234.734 us; speedup vs baseline: 1.3542x; 1.2155x over previous
//
#include <hip/hip_runtime.h>

#define NNODES 50000
#define NEDGES 800000
#define NGRAPHS 2048
#define CHUNK 4096
#define NCHUNK ((NEDGES + CHUNK - 1) / CHUNK)   // 196
#define NBUCK ((NNODES + 255) / 256)            // 196
#define BCAP 4600

typedef __attribute__((ext_vector_type(8))) short bf16x8;
typedef __attribute__((ext_vector_type(4))) float f32x4;

__device__ __forceinline__ float bf2f(ushort u) {
    return __uint_as_float(((uint)u) << 16);
}
__device__ __forceinline__ ushort f2bf(float f) {
    uint u = __float_as_uint(f);
    return (ushort)((u + 0x7fff + ((u >> 16) & 1)) >> 16);  // RNE
}

// ---------------- sort-based CSR build ----------------
// pass 1: per-chunk histogram of dst>>8
__global__ __launch_bounds__(256) void hist_pass(const int* __restrict__ dst,
                                                 int* __restrict__ blockhist) {
    __shared__ int bins[NBUCK];
    int blk = blockIdx.x;
    for (int i = threadIdx.x; i < NBUCK; i += 256) bins[i] = 0;
    __syncthreads();
    int e0 = blk * CHUNK;
    int e1 = min(e0 + CHUNK, NEDGES);
    for (int e = e0 + threadIdx.x; e < e1; e += 256)
        atomicAdd(&bins[dst[e] >> 8], 1);
    __syncthreads();
    for (int i = threadIdx.x; i < NBUCK; i += 256)
        blockhist[blk * NBUCK + i] = bins[i];
}

// pass 2: bucket sizes -> exclusive scan -> bases + cursors
__global__ void bucket_scan(const int* __restrict__ blockhist,
                            int* __restrict__ bucket_base,
                            int* __restrict__ bucket_cursor) {
    __shared__ int size_s[NBUCK];
    for (int b = threadIdx.x; b < NBUCK; b += 256) {
        int s = 0;
        for (int c = 0; c < NCHUNK; ++c) s += blockhist[c * NBUCK + b];
        size_s[b] = s;
    }
    __syncthreads();
    if (threadIdx.x == 0) {
        int run = 0;
        for (int b = 0; b < NBUCK; ++b) { int v = size_s[b]; size_s[b] = run; run += v; }
    }
    __syncthreads();
    for (int b = threadIdx.x; b < NBUCK; b += 256) {
        bucket_base[b] = size_s[b];
        bucket_cursor[b] = size_s[b];
    }
    if (threadIdx.x == 0) bucket_base[NBUCK] = NEDGES;
}

// pass 3: LDS-staged scatter into bucket regions (coalesced runs, 196 atomics/block)
__global__ __launch_bounds__(256) void scatter_pass(const int* __restrict__ src,
                                                    const int* __restrict__ dst,
                                                    int* __restrict__ bucket_cursor,
                                                    int2* __restrict__ ebuf) {
    __shared__ int bins[NBUCK];
    __shared__ int loff[NBUCK];
    __shared__ int gbase[NBUCK];
    __shared__ int lcur[NBUCK];
    __shared__ int2 stage[CHUNK];
    __shared__ int gaddr[CHUNK];
    int blk = blockIdx.x;
    int e0 = blk * CHUNK;
    int e1 = min(e0 + CHUNK, NEDGES);
    for (int i = threadIdx.x; i < NBUCK; i += 256) { bins[i] = 0; lcur[i] = 0; }
    __syncthreads();
    for (int e = e0 + threadIdx.x; e < e1; e += 256)
        atomicAdd(&bins[dst[e] >> 8], 1);
    __syncthreads();
    if (threadIdx.x == 0) {
        int run = 0;
        for (int b = 0; b < NBUCK; ++b) { loff[b] = run; run += bins[b]; }
    }
    __syncthreads();
    for (int b = threadIdx.x; b < NBUCK; b += 256)
        gbase[b] = bins[b] ? atomicAdd(&bucket_cursor[b], bins[b]) : 0;
    __syncthreads();
    for (int e = e0 + threadIdx.x; e < e1; e += 256) {
        int d = dst[e];
        int b = d >> 8;
        int p = atomicAdd(&lcur[b], 1);
        int slot = loff[b] + p;
        stage[slot] = make_int2(src[e], d);
        gaddr[slot] = gbase[b] + p;
    }
    __syncthreads();
    int cnt = e1 - e0;
    for (int i = threadIdx.x; i < cnt; i += 256)
        ebuf[gaddr[i]] = stage[i];
}

// pass 4: per-bucket counting sort -> csr_src (+ rowptr + dis from the histogram)
__global__ __launch_bounds__(256) void bucket_sort(const int2* __restrict__ ebuf,
                                                   const int* __restrict__ bucket_base,
                                                   int* __restrict__ csr_src,
                                                   int* __restrict__ rowptr,
                                                   float* __restrict__ dis) {
    __shared__ int h[256], sc[257], cur[256];
    __shared__ int srcstage[BCAP];
    int b = blockIdx.x;
    int base = bucket_base[b];
    int cnt = bucket_base[b + 1] - base;
    int t = threadIdx.x;
    h[t] = 0;
    cur[t] = 0;
    __syncthreads();
    for (int i = t; i < cnt; i += 256)
        atomicAdd(&h[ebuf[base + i].y & 255], 1);
    __syncthreads();
    if (t == 0) {
        int run = 0;
        for (int j = 0; j < 256; ++j) { sc[j] = run; run += h[j]; }
        sc[256] = run;
    }
    __syncthreads();
    int node = b * 256 + t;
    if (node <= NNODES) rowptr[node] = base + sc[t];
    if (node < NNODES) dis[node] = rsqrtf((float)(h[t] + 1));
    __syncthreads();
    if (cnt <= BCAP) {
        for (int i = t; i < cnt; i += 256) {
            int2 r = ebuf[base + i];
            int j = r.y & 255;
            int p = atomicAdd(&cur[j], 1);
            srcstage[sc[j] + p] = r.x;
        }
        __syncthreads();
        for (int i = t; i < cnt; i += 256)
            csr_src[base + i] = srcstage[i];
    } else {
        // overflow fallback (statistically never: cnt ~ N(4082, 64))
        for (int i = t; i < cnt; i += 256) {
            int2 r = ebuf[base + i];
            int j = r.y & 255;
            int p = atomicAdd(&cur[j], 1);
            csr_src[base + sc[j] + p] = r.x;
        }
    }
}

// ---------------- combined input cast + weight prep + graph bounds ----------------
__global__ void prep_all(const float* __restrict__ x, ushort* __restrict__ xb,
                         const float* __restrict__ W1, ushort* __restrict__ W1t,
                         const float* __restrict__ W2, ushort* __restrict__ W2t,
                         const float* __restrict__ W3, ushort* __restrict__ W3t,
                         const float* __restrict__ Wfc, ushort* __restrict__ Wfct,
                         const int* __restrict__ batch, int* __restrict__ gstart) {
    const int M = NNODES;
    const int KX = 80, F1 = 78, F2 = 156, F3 = 312, FC = 489;
    const int n0 = M * KX;
    const int n1 = 80 * 96, n2 = 160 * 96, n3 = 320 * 160, n4 = 496 * 320;
    int idx = blockIdx.x * blockDim.x + threadIdx.x;
    if (idx < n0) {
        int n = idx / KX, k = idx % KX;
        xb[idx] = (k < F1) ? f2bf(x[(size_t)n * F1 + k]) : (ushort)0;
        return;
    }
    idx -= n0;
    if (idx < n1) {
        int n = idx / 96, k = idx % 96;
        W1t[idx] = (k < F1 && n < F1) ? f2bf(W1[(size_t)k * F1 + n]) : (ushort)0;
        return;
    }
    idx -= n1;
    if (idx < n2) {
        int n = idx / 96, k = idx % 96;
        W2t[idx] = (k < F1 && n < F2) ? f2bf(W2[(size_t)k * F2 + n]) : (ushort)0;
        return;
    }
    idx -= n2;
    if (idx < n3) {
        int n = idx / 160, k = idx % 160;
        W3t[idx] = (k < F2 && n < F3) ? f2bf(W3[(size_t)k * F3 + n]) : (ushort)0;
        return;
    }
    idx -= n3;
    if (idx < n4) {
        int n = idx / 320, k = idx % 320;
        Wfct[idx] = (k < F3 && n < FC) ? f2bf(Wfc[(size_t)k * FC + n]) : (ushort)0;
        return;
    }
    idx -= n4;
    if (idx < M) {
        int n = idx;
        int b = batch[n];
        int bp = (n == 0) ? -1 : batch[n - 1];
        for (int gg = bp + 1; gg <= b; ++gg) gstart[gg] = n;
        if (n == M - 1) {
            for (int gg = b + 1; gg <= NGRAPHS; ++gg) gstart[gg] = M;
        }
    }
}

// ---------------- ILP gather: lanes = (sub-edge, uint4-chunk) ----------------
// csr_src only (4B/edge); nm = dis[src]*dis[node] computed in-loop.
__device__ __forceinline__ void acc8(float* acc, uint4 v, float nm) {
    acc[0] += bf2f((ushort)(v.x & 0xffff)) * nm;
    acc[1] += bf2f((ushort)(v.x >> 16)) * nm;
    acc[2] += bf2f((ushort)(v.y & 0xffff)) * nm;
    acc[3] += bf2f((ushort)(v.y >> 16)) * nm;
    acc[4] += bf2f((ushort)(v.z & 0xffff)) * nm;
    acc[5] += bf2f((ushort)(v.z >> 16)) * nm;
    acc[6] += bf2f((ushort)(v.w & 0xffff)) * nm;
    acc[7] += bf2f((ushort)(v.w >> 16)) * nm;
}

template <int CH, int STR, int SUB, int CHOUT>
__global__ __launch_bounds__(128) void gather_ilp(const uint4* __restrict__ h,
                                                  const int* __restrict__ rowptr,
                                                  const int* __restrict__ csr_src,
                                                  const float* __restrict__ dis,
                                                  uint4* __restrict__ agg) {
    int node = blockIdx.x * 2 + (threadIdx.x >> 6);
    if (node >= NNODES) return;
    int lane = threadIdx.x & 63;
    int sub = lane / CH;
    int ch = lane % CH;
    bool active = sub < SUB;
    float di = dis[node];

    float acc[8] = {};
    int beg = rowptr[node], end = rowptr[node + 1];
    for (int i = beg; i < end; i += 4 * SUB) {
        int sidx[4];
        int vld[4];
        #pragma unroll
        for (int u = 0; u < 4; ++u) {
            int e = i + u * SUB + sub;
            vld[u] = active && (e < end);
            sidx[u] = vld[u] ? csr_src[e] : 0;
        }
        uint4 av[4];
        float ds[4];
        #pragma unroll
        for (int u = 0; u < 4; ++u) {
            av[u] = vld[u] ? h[(size_t)sidx[u] * STR + ch] : make_uint4(0, 0, 0, 0);
            ds[u] = dis[sidx[u]];
        }
        #pragma unroll
        for (int u = 0; u < 4; ++u)
            acc8(acc, av[u], ds[u] * di);
    }

    float tot[8];
    #pragma unroll
    for (int j = 0; j < 8; ++j) tot[j] = acc[j];
    #pragma unroll
    for (int sb = 1; sb < SUB; ++sb) {
        int srcLane = ch + sb * CH;
        #pragma unroll
        for (int j = 0; j < 8; ++j) tot[j] += __shfl(acc[j], srcLane);
    }

    if (lane < CHOUT) {
        uint4 o = make_uint4(0, 0, 0, 0);
        if (lane < CH) {
            float d2 = di * di;
            uint4 hs = h[(size_t)node * STR + lane];
            tot[0] += bf2f((ushort)(hs.x & 0xffff)) * d2;
            tot[1] += bf2f((ushort)(hs.x >> 16)) * d2;
            tot[2] += bf2f((ushort)(hs.y & 0xffff)) * d2;
            tot[3] += bf2f((ushort)(hs.y >> 16)) * d2;
            tot[4] += bf2f((ushort)(hs.z & 0xffff)) * d2;
            tot[5] += bf2f((ushort)(hs.z >> 16)) * d2;
            tot[6] += bf2f((ushort)(hs.w & 0xffff)) * d2;
            tot[7] += bf2f((ushort)(hs.w >> 16)) * d2;
            o.x = (uint)f2bf(tot[0]) | ((uint)f2bf(tot[1]) << 16);
            o.y = (uint)f2bf(tot[2]) | ((uint)f2bf(tot[3]) << 16);
            o.z = (uint)f2bf(tot[4]) | ((uint)f2bf(tot[5]) << 16);
            o.w = (uint)f2bf(tot[6]) | ((uint)f2bf(tot[7]) << 16);
        }
        agg[(size_t)node * CHOUT + lane] = o;
    }
}

// ---------------- MFMA bf16 GEMM: C = epi(A[M][Kp] @ Wt[Np][Kp]^T) ----------------
template <int EPI>
__global__ __launch_bounds__(256) void gemm_mfma(const ushort* __restrict__ A,
                                                 const ushort* __restrict__ Bt,
                                                 ushort* __restrict__ Cb,
                                                 float* __restrict__ Cf,
                                                 const float* __restrict__ bias,
                                                 const float* __restrict__ addend,
                                                 int M, int Kp, int Np, int Nreal, int Cld) {
    __shared__ ushort Asl[64 * 32];
    __shared__ ushort Bsl[64 * 32];
    const int tid = threadIdx.x;
    const int lane = tid & 63;
    const int wid = tid >> 6;
    const int wm = (wid >> 1) * 32, wn = (wid & 1) * 32;
    const int bm = blockIdx.x * 64, bn = blockIdx.y * 64;

    const int sr = tid >> 2;
    const int sc = tid & 3;
    const int swz = sc ^ ((sr >> 1) & 3);
    const int lc = lane >> 4;

    f32x4 acc[2][2] = {};
    for (int k0 = 0; k0 < Kp; k0 += 32) {
        bf16x8 av = {};
        int gr = bm + sr;
        if (gr < M) av = *(const bf16x8*)&A[(size_t)gr * Kp + k0 + sc * 8];
        *(bf16x8*)&Asl[sr * 32 + swz * 8] = av;
        bf16x8 bv = {};
        int gn = bn + sr;
        if (gn < Np) bv = *(const bf16x8*)&Bt[(size_t)gn * Kp + k0 + sc * 8];
        *(bf16x8*)&Bsl[sr * 32 + swz * 8] = bv;
        __syncthreads();
        bf16x8 af[2], bfr[2];
        #pragma unroll
        for (int m = 0; m < 2; ++m) {
            int r = wm + m * 16 + (lane & 15);
            int pc = lc ^ ((r >> 1) & 3);
            af[m] = *(const bf16x8*)&Asl[r * 32 + pc * 8];
        }
        #pragma unroll
        for (int n = 0; n < 2; ++n) {
            int r = wn + n * 16 + (lane & 15);
            int pc = lc ^ ((r >> 1) & 3);
            bfr[n] = *(const bf16x8*)&Bsl[r * 32 + pc * 8];
        }
        #pragma unroll
        for (int m = 0; m < 2; ++m)
            #pragma unroll
            for (int n = 0; n < 2; ++n)
                acc[m][n] = __builtin_amdgcn_mfma_f32_16x16x32_bf16(af[m], bfr[n], acc[m][n], 0, 0, 0);
        __syncthreads();
    }
    #pragma unroll
    for (int m = 0; m < 2; ++m) {
        #pragma unroll
        for (int n = 0; n < 2; ++n) {
            int gc = bn + wn + n * 16 + (lane & 15);
            #pragma unroll
            for (int j = 0; j < 4; ++j) {
                int gr = bm + wm + m * 16 + (lane >> 4) * 4 + j;
                if (gr >= M) continue;
                float v = acc[m][n][j];
                if (EPI == 0) {
                    if (gc < Np) {
                        float o = (gc < Nreal) ? fmaxf(v + bias[gc], 0.f) : 0.f;
                        Cb[(size_t)gr * Cld + gc] = f2bf(o);
                    }
                } else {
                    if (gc < Nreal) {
                        float o = fmaxf(v + bias[gc], 0.f) + addend[(size_t)gr * Nreal + gc];
                        Cf[(size_t)gr * Nreal + gc] = o;
                    }
                }
            }
        }
    }
}

// ---------------- segmented max pool: block per graph, bf16 out ----------------
__global__ void pool_max_seg(const uint* __restrict__ h3, const int* __restrict__ gstart,
                             uint* __restrict__ gb, int PAIRS) {
    int g = blockIdx.x;
    int s = gstart[g], e = gstart[g + 1];
    for (int p = threadIdx.x; p < PAIRS; p += blockDim.x) {
        float mL = 0.f, mH = 0.f;  // h3 >= 0; empty graph -> 0 (isfinite guard)
        for (int n = s; n < e; ++n) {
            uint v = h3[(size_t)n * PAIRS + p];
            mL = fmaxf(mL, bf2f((ushort)(v & 0xffff)));
            mH = fmaxf(mH, bf2f((ushort)(v >> 16)));
        }
        gb[(size_t)g * PAIRS + p] = (uint)f2bf(mL) | ((uint)f2bf(mH) << 16);
    }
}

extern "C" void kernel_launch(void* const* d_in, const int* in_sizes, int n_in,
                              void* d_out, int out_size, void* d_ws, size_t ws_size,
                              hipStream_t stream) {
    const float* x     = (const float*)d_in[0];
    const int*   eidx  = (const int*)d_in[1];
    const int*   batch = (const int*)d_in[2];
    const float* drug2 = (const float*)d_in[3];
    const float* W1 = (const float*)d_in[4];
    const float* b1 = (const float*)d_in[5];
    const float* W2 = (const float*)d_in[6];
    const float* b2 = (const float*)d_in[7];
    const float* W3 = (const float*)d_in[8];
    const float* b3 = (const float*)d_in[9];
    const float* Wfc = (const float*)d_in[10];
    const float* bfc = (const float*)d_in[11];
    float* out = (float*)d_out;

    const int M = NNODES, E = NEDGES, G = NGRAPHS;
    const int F1 = 78, F2 = 156, F3 = 312, FC = 489;
    const int Kx = 80;
    const int Kp1 = 96, Np1 = 80;
    const int Kp2 = 96, Np2 = 160;
    const int Kp3 = 160, Np3 = 320;
    const int Kpf = 320, Npf = 496;

    const int* src = eidx;
    const int* dst = eidx + E;

    char* ws = (char*)d_ws;
    size_t off = 0;
    auto alloc = [&](size_t bytes) {
        void* p = ws + off;
        off += (bytes + 255) & ~(size_t)255;
        return p;
    };
    ushort* xb   = (ushort*)alloc((size_t)M * Kx * 2);
    ushort* h1   = (ushort*)alloc((size_t)M * Np1 * 2);
    ushort* h2   = (ushort*)alloc((size_t)M * Np2 * 2);
    ushort* h3   = (ushort*)alloc((size_t)M * Np3 * 2);
    ushort* agg  = (ushort*)alloc((size_t)M * Kp3 * 2);
    ushort* W1t  = (ushort*)alloc((size_t)Np1 * Kp1 * 2);
    ushort* W2t  = (ushort*)alloc((size_t)Np2 * Kp2 * 2);
    ushort* W3t  = (ushort*)alloc((size_t)Np3 * Kp3 * 2);
    ushort* Wfct = (ushort*)alloc((size_t)Npf * Kpf * 2);
    ushort* gb   = (ushort*)alloc((size_t)G * Kpf * 2);
    float* dis    = (float*)alloc((size_t)M * 4);
    int*   rowptr = (int*)alloc((size_t)(M + 1) * 4);
    int2*  ebuf   = (int2*)alloc((size_t)E * 8);
    int*   csr_src = (int*)alloc((size_t)E * 4);
    int*   blockhist = (int*)alloc((size_t)NCHUNK * NBUCK * 4);
    int*   bucket_base = (int*)alloc((size_t)(NBUCK + 1) * 4);
    int*   bucket_cursor = (int*)alloc((size_t)NBUCK * 4);
    int*   gstart = (int*)alloc((size_t)(G + 1) * 4);

    // ---- prep (xb cast + weight transposes + graph bounds), 1 launch, independent
    {
        int total = M * Kx + 80 * 96 + 160 * 96 + 320 * 160 + 496 * 320 + M;
        prep_all<<<(total + 255) / 256, 256, 0, stream>>>(
            x, xb, W1, W1t, W2, W2t, W3, W3t, Wfc, Wfct, batch, gstart);
    }

    // ---- sort-based CSR build (4 launches, no per-edge global atomics)
    hist_pass<<<NCHUNK, 256, 0, stream>>>(dst, blockhist);
    bucket_scan<<<1, 256, 0, stream>>>(blockhist, bucket_base, bucket_cursor);
    scatter_pass<<<NCHUNK, 256, 0, stream>>>(src, dst, bucket_cursor, ebuf);
    bucket_sort<<<NBUCK, 256, 0, stream>>>(ebuf, bucket_base, csr_src, rowptr, dis);

    const int GG = (M + 1) / 2;       // 2 nodes per 128-thread block
    const int GMX = (M + 63) / 64;

    // ---- layer 1: agg [M][96]; h1 = relu(agg@W1+b1) [M][80]
    gather_ilp<10, 10, 6, 12><<<GG, 128, 0, stream>>>((const uint4*)xb, rowptr, csr_src, dis, (uint4*)agg);
    gemm_mfma<0><<<dim3(GMX, (Np1 + 63) / 64), 256, 0, stream>>>(agg, W1t, h1, nullptr, b1, nullptr, M, Kp1, Np1, F1, Np1);

    // ---- layer 2: agg [M][96]; h2 = relu(agg@W2+b2) [M][160]
    gather_ilp<10, 10, 6, 12><<<GG, 128, 0, stream>>>((const uint4*)h1, rowptr, csr_src, dis, (uint4*)agg);
    gemm_mfma<0><<<dim3(GMX, (Np2 + 63) / 64), 256, 0, stream>>>(agg, W2t, h2, nullptr, b2, nullptr, M, Kp2, Np2, F2, Np2);

    // ---- layer 3: agg [M][160]; h3 = relu(agg@W3+b3) [M][320]
    gather_ilp<20, 20, 3, 20><<<GG, 128, 0, stream>>>((const uint4*)h2, rowptr, csr_src, dis, (uint4*)agg);
    gemm_mfma<0><<<dim3(GMX, Np3 / 64), 256, 0, stream>>>(agg, W3t, h3, nullptr, b3, nullptr, M, Kp3, Np3, F3, Np3);

    // ---- segmented max pool -> gb bf16 [G][320]
    pool_max_seg<<<G, 256, 0, stream>>>((const uint*)h3, gstart, (uint*)gb, Kpf / 2);

    // ---- FC: out = relu(gb@Wfc+bfc)+drug2, f32 [2048][489]
    gemm_mfma<1><<<dim3((G + 63) / 64, (Npf + 63) / 64), 256, 0, stream>>>(
        gb, Wfct, nullptr, out, bfc, drug2, G, Kpf, Npf, FC, 0);
}